// Round 17
// baseline (186.995 us; speedup 1.0000x reference)
//
#include <hip/hip_runtime.h>

typedef unsigned short ushort_t;
using bf16x8 = __attribute__((ext_vector_type(8))) short;
using f32x4  = __attribute__((ext_vector_type(4))) float;
using f32x16 = __attribute__((ext_vector_type(16))) float;
using u32x4  = __attribute__((ext_vector_type(4))) unsigned int;

#define B_  4
#define L_  2048
#define D_  1024
#define H_  16
#define HD_ 64
#define N3_ 3072
#define M1_ (B_ * L_)   // 8192

static __device__ __forceinline__ unsigned short f2bf(float f) {
    unsigned int u = __float_as_uint(f);
    unsigned int r = (u + 0x7fffu + ((u >> 16) & 1u)) >> 16;
    return (unsigned short)r;
}

static __device__ __forceinline__ unsigned int pkbf(float lo, float hi) {
    unsigned int r;
    asm("v_cvt_pk_bf16_f32 %0, %1, %2" : "=v"(r) : "v"(lo), "v"(hi));
    return r;
}

static __device__ __forceinline__ void plswap(unsigned int& a, unsigned int& b) {
    asm volatile("v_permlane32_swap_b32 %0, %1" : "+v"(a), "+v"(b));
}

static __device__ __forceinline__ void async16(const void* g, const void* l) {
    __builtin_amdgcn_global_load_lds(
        (const __attribute__((address_space(1))) void*)g,
        (__attribute__((address_space(3))) void*)l, 16, 0, 0);
}

// ---------------- fused prep: x->bf16 + both weight transposes ---------
__global__ __launch_bounds__(256) void prep_kernel(
    const float* __restrict__ x, const float* __restrict__ Wqkv,
    const float* __restrict__ Wout, ushort4* __restrict__ xb,
    unsigned short* __restrict__ wqkvT, unsigned short* __restrict__ woutT) {
    __shared__ float tile[32][33];
    const int bid = blockIdx.x;
    const int tid = threadIdx.x;
    if (bid < 8192) {
        const int i = bid * 256 + tid;
        float4 v = ((const float4*)x)[i];
        ushort4 o;
        o.x = f2bf(v.x); o.y = f2bf(v.y); o.z = f2bf(v.z); o.w = f2bf(v.w);
        xb[i] = o;
        return;
    }
    const float* src;
    unsigned short* dst;
    int cols, c0, r0;
    if (bid < 8192 + 3072) {
        const int t = bid - 8192;
        src = Wqkv; dst = wqkvT; cols = N3_;
        c0 = (t % 96) * 32; r0 = (t / 96) * 32;
    } else {
        const int t = bid - 8192 - 3072;
        src = Wout; dst = woutT; cols = D_;
        c0 = (t % 32) * 32; r0 = (t / 32) * 32;
    }
    const int tx = tid & 31, ty = tid >> 5;      // 32 x 8
    #pragma unroll
    for (int j = 0; j < 32; j += 8)
        tile[ty + j][tx] = src[(size_t)(r0 + ty + j) * cols + c0 + tx];
    __syncthreads();
    #pragma unroll
    for (int j = 0; j < 32; j += 8)
        dst[(size_t)(c0 + ty + j) * D_ + r0 + tx] = f2bf(tile[tx][ty + j]);
}

// ======= QKV GEMM: 256x128 tile, 8 waves (2Mx4N), BK=32, 3-buf LDS =====
// (R7..R16 proven: 77 us, conflicts 0, 2 blocks/CU.)
// Q is PRE-SCALED by 0.125*log2(e) so attention softmax is bare exp2.
__global__ __launch_bounds__(512, 4) void gemm256_qkv_kernel(
    const unsigned short* __restrict__ A, const unsigned short* __restrict__ BT,
    unsigned short* __restrict__ qb, unsigned short* __restrict__ kb,
    unsigned short* __restrict__ vb) {
    constexpr int K = 1024, BK = 32, NT = K / BK;   // 32 K-tiles
    constexpr int NBX = N3_ / 128;                  // 24
    constexpr int NWG = (M1_ / 256) * NBX;          // 768
    __shared__ __align__(16) unsigned short ldsA[3][256 * BK];  // 48 KiB
    __shared__ __align__(16) unsigned short ldsB[3][128 * BK];  // 24 KiB

    const int tid = threadIdx.x;          // 0..511
    const int w = tid >> 6, lane = tid & 63;
    const int wr = w >> 2, wc = w & 3;    // wave grid 2(M) x 4(N)
    const int lg = lane >> 4, ll = lane & 15;

    const int bid = blockIdx.x;
    const int swz = (bid & 7) * (NWG / 8) + (bid >> 3);
    const int m0 = (swz / NBX) * 256, n0 = (swz % NBX) * 128;

    const int srow = tid >> 2;
    const int scol = (((tid & 3) ^ ((tid >> 3) & 3)) * 8);
    const int rxor = ((ll >> 1) & 3) * 8;

    f32x4 acc[8][2] = {};

    #define STAGE(kt_) do {                                                  \
        const int b3_ = (kt_) % 3;                                           \
        const size_t koff_ = (size_t)(kt_) * BK + scol;                      \
        async16(&A[(size_t)(m0 + srow) * K + koff_],       &ldsA[b3_][tid * 8]);        \
        async16(&A[(size_t)(m0 + 128 + srow) * K + koff_], &ldsA[b3_][4096 + tid * 8]); \
        async16(&BT[(size_t)(n0 + srow) * K + koff_],      &ldsB[b3_][tid * 8]);        \
    } while (0)

    STAGE(0);
    STAGE(1);

    #pragma unroll 1
    for (int kt = 0; kt < NT; ++kt) {
        if (kt + 2 < NT) {
            STAGE(kt + 2);
            asm volatile("s_waitcnt vmcnt(6)" ::: "memory");
        } else if (kt + 1 < NT) {
            asm volatile("s_waitcnt vmcnt(3)" ::: "memory");
        } else {
            asm volatile("s_waitcnt vmcnt(0)" ::: "memory");
        }
        __builtin_amdgcn_s_barrier();
        __builtin_amdgcn_sched_barrier(0);

        const unsigned short* Ab = &ldsA[kt % 3][0];
        const unsigned short* Bb = &ldsB[kt % 3][0];
        bf16x8 bfr[2];
        #pragma unroll
        for (int j = 0; j < 2; ++j)
            bfr[j] = *(const bf16x8*)&Bb[(wc * 32 + j * 16 + ll) * BK + (lg * 8 ^ rxor)];
        bf16x8 af[8];
        #pragma unroll
        for (int i = 0; i < 8; ++i)
            af[i] = *(const bf16x8*)&Ab[(wr * 128 + i * 16 + ll) * BK + (lg * 8 ^ rxor)];

        __builtin_amdgcn_s_setprio(1);
        #pragma unroll
        for (int i = 0; i < 8; ++i)
            #pragma unroll
            for (int j = 0; j < 2; ++j)
                acc[i][j] = __builtin_amdgcn_mfma_f32_16x16x32_bf16(
                    af[i], bfr[j], acc[i][j], 0, 0, 0);
        __builtin_amdgcn_s_setprio(0);
        __builtin_amdgcn_s_barrier();
    }
    #undef STAGE

    // ---- epilogue: scatter to fragment-order q/k/v ----
    const float QSCALE = 0.18033688011112042f;   // 0.125 * log2(e)
    #pragma unroll
    for (int mi = 0; mi < 8; ++mi) {
        const int mb = m0 + wr * 128 + mi * 16 + lg * 4;
        #pragma unroll
        for (int ni = 0; ni < 2; ++ni) {
            const int n = n0 + wc * 32 + ni * 16 + ll;
            const int s = n >> 10, h = (n >> 6) & 15, hd = n & 63;
            if (s == 2) {
                const int b = mb >> 11, l = mb & 2047;
                const size_t base = (size_t)(b * H_ + h) * (L_ * HD_);
                ushort4 pk;
                pk.x = f2bf(acc[mi][ni][0]);
                pk.y = f2bf(acc[mi][ni][1]);
                pk.z = f2bf(acc[mi][ni][2]);
                pk.w = f2bf(acc[mi][ni][3]);
                *(ushort4*)&vb[base + (l >> 5) * 2048 + ((l >> 4) & 1) * 1024 +
                               ((l >> 3) & 1) * 512 + hd * 8 + (l & 7)] = pk;
            } else {
                #pragma unroll
                for (int r = 0; r < 4; ++r) {
                    const int m = mb + r;
                    const int b = m >> 11, l = m & 2047;
                    const size_t base = (size_t)(b * H_ + h) * (L_ * HD_);
                    const size_t o = base + (l >> 5) * 2048 + (hd >> 4) * 512 +
                                     ((hd >> 3) & 1) * 256 + (l & 31) * 8 + (hd & 7);
                    float v = acc[mi][ni][r];
                    if (s == 0) qb[o] = f2bf(v * QSCALE);
                    else        kb[o] = f2bf(v);
                }
            }
        }
    }
}

// ---------------- out-proj GEMM (128^2, 2 blocks/CU) -------------------
__global__ __launch_bounds__(256) void gemm_bt_kernel(
    const unsigned short* __restrict__ A, const unsigned short* __restrict__ BT,
    float* __restrict__ outp, const float* __restrict__ bias) {
    constexpr int K = 1024;
    __shared__ unsigned short As[128 * 32];
    __shared__ unsigned short Bs[128 * 32];
    const int tid = threadIdx.x, w = tid >> 6, lane = tid & 63;
    const int m0 = blockIdx.y * 128, n0 = blockIdx.x * 128;
    const int wm = (w >> 1) * 64, wn = (w & 1) * 64;
    const int lg = lane >> 4, ll = lane & 15;
    const int scol = (((lane & 3) ^ ((lane >> 3) & 3)) * 8);
    const int rxor = ((ll >> 1) & 3) * 8;

    f32x4 acc[4][4] = {};

    for (int k0 = 0; k0 < K; k0 += 32) {
        #pragma unroll
        for (int j = 0; j < 2; ++j) {
            int row = w * 32 + j * 16 + (lane >> 2);
            async16(&A[(size_t)(m0 + row) * K + k0 + scol], &As[(w * 32 + j * 16) * 32]);
            async16(&BT[(size_t)(n0 + row) * K + k0 + scol], &Bs[(w * 32 + j * 16) * 32]);
        }
        __syncthreads();
        bf16x8 af[4], bfr[4];
        #pragma unroll
        for (int i = 0; i < 4; ++i) {
            af[i]  = *(const bf16x8*)&As[(wm + i * 16 + ll) * 32 + (lg * 8 ^ rxor)];
            bfr[i] = *(const bf16x8*)&Bs[(wn + i * 16 + ll) * 32 + (lg * 8 ^ rxor)];
        }
        #pragma unroll
        for (int mi = 0; mi < 4; ++mi)
            #pragma unroll
            for (int ni = 0; ni < 4; ++ni)
                acc[mi][ni] = __builtin_amdgcn_mfma_f32_16x16x32_bf16(
                    af[mi], bfr[ni], acc[mi][ni], 0, 0, 0);
        __syncthreads();
    }

    #pragma unroll
    for (int mi = 0; mi < 4; ++mi)
        #pragma unroll
        for (int ni = 0; ni < 4; ++ni)
            #pragma unroll
            for (int r = 0; r < 4; ++r) {
                int m = m0 + wm + mi * 16 + lg * 4 + r;
                int n = n0 + wn + ni * 16 + ll;
                outp[(size_t)m * D_ + n] = acc[mi][ni][r] + bias[n];
            }
}

// ------- flash attention: symmetric-pair blocks + kv-split x4 ----------
// Grid 2048 blocks x 8 waves. Block g (0..31) of bh handles qtiles
// {g, 63-g} -> EVERY block totals 65 tile-units (perfect balance).
// Wave (qsel, s): qtile = qsel ? 63-g : g; kv-tiles t = s, s+4, ... <= qt
// (worst chain 32 -> 16). Bare-exp2 softmax (Q pre-scaled) => partials
// exactly additive; 2-stage LDS merge (s1->s0, s3->s2; then s2->s0),
// zero barriers in the loop. VGPR ~60, LDS ~36 KB -> 4 blocks/CU.
__global__ __launch_bounds__(512, 4) void attn_kernel(
    const unsigned short* __restrict__ qbuf, const unsigned short* __restrict__ kbuf,
    const unsigned short* __restrict__ vbuf, unsigned short* __restrict__ obuf) {
    __shared__ float Xo[2][2][64][33];
    __shared__ float Xs[2][2][64];
    __shared__ float Sdl[2][32];

    const int tid = threadIdx.x;
    const int w = tid >> 6, lane = tid & 63;
    const int qsel = w >> 2, s = w & 3;
    const int lq = lane & 31;
    const int hi = lane >> 5;

    const int bid = blockIdx.x;
    const int g  = bid >> 6;        // 0..31
    const int bh = bid & 63;        // bh%8 -> XCD locality preserved
    const int qt = qsel ? (63 - g) : g;
    const int q0 = qt * 32;

    const unsigned short* Qf = qbuf + (size_t)bh * (L_ * HD_);
    const unsigned short* Kf = kbuf + (size_t)bh * (L_ * HD_);
    const unsigned short* Vf = vbuf + (size_t)bh * (L_ * HD_);

    bf16x8 qf[4];
    #pragma unroll
    for (int c = 0; c < 4; ++c)
        qf[c] = *(const bf16x8*)&Qf[qt * 2048 + c * 512 + hi * 256 + lq * 8];

    f32x16 oa0 = {}, oa1 = {};
    float sden = 0.f;

    // this wave's kv-tiles: t = s, s+4, ... <= qt
    bf16x8 kf[4];
    if (s <= qt) {
        #pragma unroll
        for (int c = 0; c < 4; ++c)
            kf[c] = *(const bf16x8*)&Kf[s * 2048 + c * 512 + hi * 256 + lq * 8];
    }

    #pragma unroll 1
    for (int t = s; t <= qt; t += 4) {
        bf16x8 v0f[2], v1f[2];
        #pragma unroll
        for (int c = 0; c < 2; ++c) {
            v0f[c] = *(const bf16x8*)&Vf[t * 2048 + c * 1024 + hi * 512 + lq * 8];
            v1f[c] = *(const bf16x8*)&Vf[t * 2048 + c * 1024 + hi * 512 + 256 + lq * 8];
        }
        bf16x8 nk[4];
        const bool more = (t + 4 <= qt);
        if (more) {
            #pragma unroll
            for (int c = 0; c < 4; ++c)
                nk[c] = *(const bf16x8*)&Kf[(t + 4) * 2048 + c * 512 + hi * 256 + lq * 8];
        }

        f32x16 st = {};
        __builtin_amdgcn_s_setprio(1);
        #pragma unroll
        for (int c = 0; c < 4; ++c)
            st = __builtin_amdgcn_mfma_f32_32x32x16_bf16(kf[c], qf[c], st, 0, 0, 0);
        __builtin_amdgcn_s_setprio(0);

        float pp[16];
        float rs = 0.f;
        const bool diag = (t == qt);
        #pragma unroll
        for (int r = 0; r < 16; ++r) {
            float pv = exp2f(st[r]);           // Q pre-scaled
            if (diag) {
                int kv = (r & 3) + 8 * (r >> 2) + 4 * hi;
                if (kv > lq) pv = 0.f;
            }
            pp[r] = pv;
            rs += pv;
        }
        rs += __shfl_xor(rs, 32);
        sden += rs;

        unsigned int a0 = pkbf(pp[0],  pp[1]),  a1 = pkbf(pp[2],  pp[3]);
        unsigned int b0 = pkbf(pp[4],  pp[5]),  b1 = pkbf(pp[6],  pp[7]);
        unsigned int c0 = pkbf(pp[8],  pp[9]),  c1 = pkbf(pp[10], pp[11]);
        unsigned int d0 = pkbf(pp[12], pp[13]), d1 = pkbf(pp[14], pp[15]);
        plswap(a0, b0); plswap(a1, b1); plswap(c0, d0); plswap(c1, d1);
        u32x4 t0 = {a0, a1, b0, b1};
        u32x4 t1 = {c0, c1, d0, d1};
        bf16x8 pa0 = __builtin_bit_cast(bf16x8, t0);
        bf16x8 pa1 = __builtin_bit_cast(bf16x8, t1);

        __builtin_amdgcn_s_setprio(1);
        oa0 = __builtin_amdgcn_mfma_f32_32x32x16_bf16(pa0, v0f[0], oa0, 0, 0, 0);
        oa1 = __builtin_amdgcn_mfma_f32_32x32x16_bf16(pa0, v1f[0], oa1, 0, 0, 0);
        oa0 = __builtin_amdgcn_mfma_f32_32x32x16_bf16(pa1, v0f[1], oa0, 0, 0, 0);
        oa1 = __builtin_amdgcn_mfma_f32_32x32x16_bf16(pa1, v1f[1], oa1, 0, 0, 0);
        __builtin_amdgcn_s_setprio(0);

        if (more) {
            #pragma unroll
            for (int c = 0; c < 4; ++c) kf[c] = nk[c];
        }
    }

    // ---- 2-stage additive merge (partials exact: same zero shift) ----
    // stage 1: s=1 -> s=0 (slot 0), s=3 -> s=2 (slot 1)
    if (s == 1 || s == 3) {
        const int slot = s >> 1;
        #pragma unroll
        for (int r = 0; r < 16; ++r) {
            Xo[qsel][slot][lane][r]      = oa0[r];
            Xo[qsel][slot][lane][16 + r] = oa1[r];
        }
        Xs[qsel][slot][lane] = sden;
    }
    __syncthreads();
    if (s == 0 || s == 2) {
        const int slot = s >> 1;
        #pragma unroll
        for (int r = 0; r < 16; ++r) {
            oa0[r] += Xo[qsel][slot][lane][r];
            oa1[r] += Xo[qsel][slot][lane][16 + r];
        }
        sden += Xs[qsel][slot][lane];
    }
    __syncthreads();
    // stage 2: s=2 -> s=0 (slot 1)
    if (s == 2) {
        #pragma unroll
        for (int r = 0; r < 16; ++r) {
            Xo[qsel][1][lane][r]      = oa0[r];
            Xo[qsel][1][lane][16 + r] = oa1[r];
        }
        Xs[qsel][1][lane] = sden;
    }
    __syncthreads();
    if (s == 0) {
        #pragma unroll
        for (int r = 0; r < 16; ++r) {
            oa0[r] += Xo[qsel][1][lane][r];
            oa1[r] += Xo[qsel][1][lane][16 + r];
        }
        sden += Xs[qsel][1][lane];

        if (hi == 0) Sdl[qsel][lq] = 1.0f / sden;
        __builtin_amdgcn_s_waitcnt(0);   // same-wave LDS visibility

        const int b = bh >> 4, h = bh & 15;
        #pragma unroll
        for (int r = 0; r < 16; ++r) {
            int q = (r & 3) + 8 * (r >> 2) + 4 * hi;
            float inv = Sdl[qsel][q];
            size_t row = (size_t)(b * L_ + q0 + q) * D_ + h * HD_;
            obuf[row + lq]      = f2bf(oa0[r] * inv);
            obuf[row + 32 + lq] = f2bf(oa1[r] * inv);
        }
    }
}

extern "C" void kernel_launch(void* const* d_in, const int* in_sizes, int n_in,
                              void* d_out, int out_size, void* d_ws, size_t ws_size,
                              hipStream_t stream) {
    const float* x    = (const float*)d_in[0];
    const float* Wqkv = (const float*)d_in[1];
    const float* Wout = (const float*)d_in[2];
    const float* bout = (const float*)d_in[3];
    float* out = (float*)d_out;

    char* ws = (char*)d_ws;
    size_t off = 0;
    unsigned short* xb     = (unsigned short*)(ws + off); off += (size_t)M1_ * D_ * 2;   // 16MB
    unsigned short* wqkvT  = (unsigned short*)(ws + off); off += (size_t)N3_ * D_ * 2;   // 6MB
    unsigned short* woutT  = (unsigned short*)(ws + off); off += (size_t)D_ * D_ * 2;    // 2MB
    unsigned short* qb     = (unsigned short*)(ws + off); off += (size_t)B_ * H_ * L_ * HD_ * 2;
    unsigned short* kb     = (unsigned short*)(ws + off); off += (size_t)B_ * H_ * L_ * HD_ * 2;
    unsigned short* vb     = (unsigned short*)(ws + off); off += (size_t)B_ * H_ * L_ * HD_ * 2;
    unsigned short* attnb  = (unsigned short*)(ws + off); off += (size_t)M1_ * D_ * 2;

    // pass 0: fused conversions (x->bf16, Wqkv^T, Wout^T) — one launch
    prep_kernel<<<dim3(8192 + 3072 + 1024), 256, 0, stream>>>(
        x, Wqkv, Wout, (ushort4*)xb, wqkvT, woutT);

    // pass 1: QKV projection (256x128, 3-buf, 768 blocks), Q pre-scaled
    gemm256_qkv_kernel<<<dim3((M1_ / 256) * (N3_ / 128)), 512, 0, stream>>>(
        xb, wqkvT, qb, kb, vb);

    // pass 2: causal flash attention (symmetric pairs, kv-split x4)
    attn_kernel<<<dim3(32 * 64), 512, 0, stream>>>(qb, kb, vb, attnb);

    // pass 3: output projection + bias (128^2, 512 blocks = 2/CU)
    gemm_bt_kernel<<<dim3(D_ / 128, M1_ / 128), 256, 0, stream>>>(
        attnb, woutT, out, bout);
}

// Round 18
// 175.259 us; speedup vs baseline: 1.0670x; 1.0670x over previous
//
#include <hip/hip_runtime.h>

typedef unsigned short ushort_t;
using bf16x8 = __attribute__((ext_vector_type(8))) short;
using f32x4  = __attribute__((ext_vector_type(4))) float;
using f32x16 = __attribute__((ext_vector_type(16))) float;
using u32x4  = __attribute__((ext_vector_type(4))) unsigned int;

#define B_  4
#define L_  2048
#define D_  1024
#define H_  16
#define HD_ 64
#define N3_ 3072
#define M1_ (B_ * L_)   // 8192

static __device__ __forceinline__ unsigned short f2bf(float f) {
    unsigned int u = __float_as_uint(f);
    unsigned int r = (u + 0x7fffu + ((u >> 16) & 1u)) >> 16;
    return (unsigned short)r;
}

static __device__ __forceinline__ unsigned int pkbf(float lo, float hi) {
    unsigned int r;
    asm("v_cvt_pk_bf16_f32 %0, %1, %2" : "=v"(r) : "v"(lo), "v"(hi));
    return r;
}

static __device__ __forceinline__ void plswap(unsigned int& a, unsigned int& b) {
    asm volatile("v_permlane32_swap_b32 %0, %1" : "+v"(a), "+v"(b));
}

static __device__ __forceinline__ void async16(const void* g, const void* l) {
    __builtin_amdgcn_global_load_lds(
        (const __attribute__((address_space(1))) void*)g,
        (__attribute__((address_space(3))) void*)l, 16, 0, 0);
}

// ---------------- fused prep: x->bf16 + both weight transposes ---------
__global__ __launch_bounds__(256) void prep_kernel(
    const float* __restrict__ x, const float* __restrict__ Wqkv,
    const float* __restrict__ Wout, ushort4* __restrict__ xb,
    unsigned short* __restrict__ wqkvT, unsigned short* __restrict__ woutT) {
    __shared__ float tile[32][33];
    const int bid = blockIdx.x;
    const int tid = threadIdx.x;
    if (bid < 8192) {
        const int i = bid * 256 + tid;
        float4 v = ((const float4*)x)[i];
        ushort4 o;
        o.x = f2bf(v.x); o.y = f2bf(v.y); o.z = f2bf(v.z); o.w = f2bf(v.w);
        xb[i] = o;
        return;
    }
    const float* src;
    unsigned short* dst;
    int cols, c0, r0;
    if (bid < 8192 + 3072) {
        const int t = bid - 8192;
        src = Wqkv; dst = wqkvT; cols = N3_;
        c0 = (t % 96) * 32; r0 = (t / 96) * 32;
    } else {
        const int t = bid - 8192 - 3072;
        src = Wout; dst = woutT; cols = D_;
        c0 = (t % 32) * 32; r0 = (t / 32) * 32;
    }
    const int tx = tid & 31, ty = tid >> 5;      // 32 x 8
    #pragma unroll
    for (int j = 0; j < 32; j += 8)
        tile[ty + j][tx] = src[(size_t)(r0 + ty + j) * cols + c0 + tx];
    __syncthreads();
    #pragma unroll
    for (int j = 0; j < 32; j += 8)
        dst[(size_t)(c0 + ty + j) * D_ + r0 + tx] = f2bf(tile[tx][ty + j]);
}

// ======= QKV GEMM: 256x128 tile, 8 waves (2Mx4N), BK=32, 3-buf LDS =====
// (R7..R16 proven: 77 us, conflicts 0, 2 blocks/CU.)
// Q is PRE-SCALED by 0.125*log2(e) so attention softmax is bare exp2.
__global__ __launch_bounds__(512, 4) void gemm256_qkv_kernel(
    const unsigned short* __restrict__ A, const unsigned short* __restrict__ BT,
    unsigned short* __restrict__ qb, unsigned short* __restrict__ kb,
    unsigned short* __restrict__ vb) {
    constexpr int K = 1024, BK = 32, NT = K / BK;   // 32 K-tiles
    constexpr int NBX = N3_ / 128;                  // 24
    constexpr int NWG = (M1_ / 256) * NBX;          // 768
    __shared__ __align__(16) unsigned short ldsA[3][256 * BK];  // 48 KiB
    __shared__ __align__(16) unsigned short ldsB[3][128 * BK];  // 24 KiB

    const int tid = threadIdx.x;          // 0..511
    const int w = tid >> 6, lane = tid & 63;
    const int wr = w >> 2, wc = w & 3;    // wave grid 2(M) x 4(N)
    const int lg = lane >> 4, ll = lane & 15;

    const int bid = blockIdx.x;
    const int swz = (bid & 7) * (NWG / 8) + (bid >> 3);
    const int m0 = (swz / NBX) * 256, n0 = (swz % NBX) * 128;

    const int srow = tid >> 2;
    const int scol = (((tid & 3) ^ ((tid >> 3) & 3)) * 8);
    const int rxor = ((ll >> 1) & 3) * 8;

    f32x4 acc[8][2] = {};

    #define STAGE(kt_) do {                                                  \
        const int b3_ = (kt_) % 3;                                           \
        const size_t koff_ = (size_t)(kt_) * BK + scol;                      \
        async16(&A[(size_t)(m0 + srow) * K + koff_],       &ldsA[b3_][tid * 8]);        \
        async16(&A[(size_t)(m0 + 128 + srow) * K + koff_], &ldsA[b3_][4096 + tid * 8]); \
        async16(&BT[(size_t)(n0 + srow) * K + koff_],      &ldsB[b3_][tid * 8]);        \
    } while (0)

    STAGE(0);
    STAGE(1);

    #pragma unroll 1
    for (int kt = 0; kt < NT; ++kt) {
        if (kt + 2 < NT) {
            STAGE(kt + 2);
            asm volatile("s_waitcnt vmcnt(6)" ::: "memory");
        } else if (kt + 1 < NT) {
            asm volatile("s_waitcnt vmcnt(3)" ::: "memory");
        } else {
            asm volatile("s_waitcnt vmcnt(0)" ::: "memory");
        }
        __builtin_amdgcn_s_barrier();
        __builtin_amdgcn_sched_barrier(0);

        const unsigned short* Ab = &ldsA[kt % 3][0];
        const unsigned short* Bb = &ldsB[kt % 3][0];
        bf16x8 bfr[2];
        #pragma unroll
        for (int j = 0; j < 2; ++j)
            bfr[j] = *(const bf16x8*)&Bb[(wc * 32 + j * 16 + ll) * BK + (lg * 8 ^ rxor)];
        bf16x8 af[8];
        #pragma unroll
        for (int i = 0; i < 8; ++i)
            af[i] = *(const bf16x8*)&Ab[(wr * 128 + i * 16 + ll) * BK + (lg * 8 ^ rxor)];

        __builtin_amdgcn_s_setprio(1);
        #pragma unroll
        for (int i = 0; i < 8; ++i)
            #pragma unroll
            for (int j = 0; j < 2; ++j)
                acc[i][j] = __builtin_amdgcn_mfma_f32_16x16x32_bf16(
                    af[i], bfr[j], acc[i][j], 0, 0, 0);
        __builtin_amdgcn_s_setprio(0);
        __builtin_amdgcn_s_barrier();
    }
    #undef STAGE

    // ---- epilogue: scatter to fragment-order q/k/v ----
    const float QSCALE = 0.18033688011112042f;   // 0.125 * log2(e)
    #pragma unroll
    for (int mi = 0; mi < 8; ++mi) {
        const int mb = m0 + wr * 128 + mi * 16 + lg * 4;
        #pragma unroll
        for (int ni = 0; ni < 2; ++ni) {
            const int n = n0 + wc * 32 + ni * 16 + ll;
            const int s = n >> 10, h = (n >> 6) & 15, hd = n & 63;
            if (s == 2) {
                const int b = mb >> 11, l = mb & 2047;
                const size_t base = (size_t)(b * H_ + h) * (L_ * HD_);
                ushort4 pk;
                pk.x = f2bf(acc[mi][ni][0]);
                pk.y = f2bf(acc[mi][ni][1]);
                pk.z = f2bf(acc[mi][ni][2]);
                pk.w = f2bf(acc[mi][ni][3]);
                *(ushort4*)&vb[base + (l >> 5) * 2048 + ((l >> 4) & 1) * 1024 +
                               ((l >> 3) & 1) * 512 + hd * 8 + (l & 7)] = pk;
            } else {
                #pragma unroll
                for (int r = 0; r < 4; ++r) {
                    const int m = mb + r;
                    const int b = m >> 11, l = m & 2047;
                    const size_t base = (size_t)(b * H_ + h) * (L_ * HD_);
                    const size_t o = base + (l >> 5) * 2048 + (hd >> 4) * 512 +
                                     ((hd >> 3) & 1) * 256 + (l & 31) * 8 + (hd & 7);
                    float v = acc[mi][ni][r];
                    if (s == 0) qb[o] = f2bf(v * QSCALE);
                    else        kb[o] = f2bf(v);
                }
            }
        }
    }
}

// ---------------- out-proj GEMM (128^2, 2 blocks/CU) -------------------
__global__ __launch_bounds__(256) void gemm_bt_kernel(
    const unsigned short* __restrict__ A, const unsigned short* __restrict__ BT,
    float* __restrict__ outp, const float* __restrict__ bias) {
    constexpr int K = 1024;
    __shared__ unsigned short As[128 * 32];
    __shared__ unsigned short Bs[128 * 32];
    const int tid = threadIdx.x, w = tid >> 6, lane = tid & 63;
    const int m0 = blockIdx.y * 128, n0 = blockIdx.x * 128;
    const int wm = (w >> 1) * 64, wn = (w & 1) * 64;
    const int lg = lane >> 4, ll = lane & 15;
    const int scol = (((lane & 3) ^ ((lane >> 3) & 3)) * 8);
    const int rxor = ((ll >> 1) & 3) * 8;

    f32x4 acc[4][4] = {};

    for (int k0 = 0; k0 < K; k0 += 32) {
        #pragma unroll
        for (int j = 0; j < 2; ++j) {
            int row = w * 32 + j * 16 + (lane >> 2);
            async16(&A[(size_t)(m0 + row) * K + k0 + scol], &As[(w * 32 + j * 16) * 32]);
            async16(&BT[(size_t)(n0 + row) * K + k0 + scol], &Bs[(w * 32 + j * 16) * 32]);
        }
        __syncthreads();
        bf16x8 af[4], bfr[4];
        #pragma unroll
        for (int i = 0; i < 4; ++i) {
            af[i]  = *(const bf16x8*)&As[(wm + i * 16 + ll) * 32 + (lg * 8 ^ rxor)];
            bfr[i] = *(const bf16x8*)&Bs[(wn + i * 16 + ll) * 32 + (lg * 8 ^ rxor)];
        }
        #pragma unroll
        for (int mi = 0; mi < 4; ++mi)
            #pragma unroll
            for (int ni = 0; ni < 4; ++ni)
                acc[mi][ni] = __builtin_amdgcn_mfma_f32_16x16x32_bf16(
                    af[mi], bfr[ni], acc[mi][ni], 0, 0, 0);
        __syncthreads();
    }

    #pragma unroll
    for (int mi = 0; mi < 4; ++mi)
        #pragma unroll
        for (int ni = 0; ni < 4; ++ni)
            #pragma unroll
            for (int r = 0; r < 4; ++r) {
                int m = m0 + wm + mi * 16 + lg * 4 + r;
                int n = n0 + wn + ni * 16 + ll;
                outp[(size_t)m * D_ + n] = acc[mi][ni][r] + bias[n];
            }
}

// ------- flash attention: kv-split x2 (R15/R16-proven) -----------------
// 8 waves/block: wave pair (p, s) — qtile qt=(15-grp)*4+p, wave s does
// kv-tiles t = s, s+2, ... <= qt. Bare-exp2 softmax (Q pre-scaled) makes
// partials exactly additive: one end-of-kernel LDS merge + single
// __syncthreads, zero barriers in the loop. launch_bounds(512,4).
__global__ __launch_bounds__(512, 4) void attn_kernel(
    const unsigned short* __restrict__ qbuf, const unsigned short* __restrict__ kbuf,
    const unsigned short* __restrict__ vbuf, unsigned short* __restrict__ obuf) {
    __shared__ float Xo[4][64][33];   // pair-exchange, padded
    __shared__ float Xs[4][64];
    __shared__ float Sdl[4][32];

    const int tid = threadIdx.x;
    const int w = tid >> 6, lane = tid & 63;
    const int p = w >> 1, s = w & 1;
    const int lq = lane & 31;
    const int hi = lane >> 5;

    const int bid = blockIdx.x;
    const int grp = bid >> 6;       // 0..15, heavy qtiles first
    const int bh  = bid & 63;
    const int qt  = (15 - grp) * 4 + p;   // 0..63
    const int q0  = qt * 32;

    const unsigned short* Qf = qbuf + (size_t)bh * (L_ * HD_);
    const unsigned short* Kf = kbuf + (size_t)bh * (L_ * HD_);
    const unsigned short* Vf = vbuf + (size_t)bh * (L_ * HD_);

    bf16x8 qf[4];
    #pragma unroll
    for (int c = 0; c < 4; ++c)
        qf[c] = *(const bf16x8*)&Qf[qt * 2048 + c * 512 + hi * 256 + lq * 8];

    f32x16 oa0 = {}, oa1 = {};
    float sden = 0.f;

    // this wave's kv-tiles: t = s, s+2, ... <= qt
    bf16x8 kf[4];
    if (s <= qt) {
        #pragma unroll
        for (int c = 0; c < 4; ++c)
            kf[c] = *(const bf16x8*)&Kf[s * 2048 + c * 512 + hi * 256 + lq * 8];
    }

    #pragma unroll 1
    for (int t = s; t <= qt; t += 2) {
        bf16x8 v0f[2], v1f[2];
        #pragma unroll
        for (int c = 0; c < 2; ++c) {
            v0f[c] = *(const bf16x8*)&Vf[t * 2048 + c * 1024 + hi * 512 + lq * 8];
            v1f[c] = *(const bf16x8*)&Vf[t * 2048 + c * 1024 + hi * 512 + 256 + lq * 8];
        }
        bf16x8 nk[4];
        const bool more = (t + 2 <= qt);
        if (more) {
            #pragma unroll
            for (int c = 0; c < 4; ++c)
                nk[c] = *(const bf16x8*)&Kf[(t + 2) * 2048 + c * 512 + hi * 256 + lq * 8];
        }

        f32x16 st = {};
        __builtin_amdgcn_s_setprio(1);
        #pragma unroll
        for (int c = 0; c < 4; ++c)
            st = __builtin_amdgcn_mfma_f32_32x32x16_bf16(kf[c], qf[c], st, 0, 0, 0);
        __builtin_amdgcn_s_setprio(0);

        float pp[16];
        float rs = 0.f;
        const bool diag = (t == qt);
        #pragma unroll
        for (int r = 0; r < 16; ++r) {
            float pv = exp2f(st[r]);           // Q pre-scaled
            if (diag) {
                int kv = (r & 3) + 8 * (r >> 2) + 4 * hi;
                if (kv > lq) pv = 0.f;
            }
            pp[r] = pv;
            rs += pv;
        }
        rs += __shfl_xor(rs, 32);
        sden += rs;

        unsigned int a0 = pkbf(pp[0],  pp[1]),  a1 = pkbf(pp[2],  pp[3]);
        unsigned int b0 = pkbf(pp[4],  pp[5]),  b1 = pkbf(pp[6],  pp[7]);
        unsigned int c0 = pkbf(pp[8],  pp[9]),  c1 = pkbf(pp[10], pp[11]);
        unsigned int d0 = pkbf(pp[12], pp[13]), d1 = pkbf(pp[14], pp[15]);
        plswap(a0, b0); plswap(a1, b1); plswap(c0, d0); plswap(c1, d1);
        u32x4 t0 = {a0, a1, b0, b1};
        u32x4 t1 = {c0, c1, d0, d1};
        bf16x8 pa0 = __builtin_bit_cast(bf16x8, t0);
        bf16x8 pa1 = __builtin_bit_cast(bf16x8, t1);

        __builtin_amdgcn_s_setprio(1);
        oa0 = __builtin_amdgcn_mfma_f32_32x32x16_bf16(pa0, v0f[0], oa0, 0, 0, 0);
        oa1 = __builtin_amdgcn_mfma_f32_32x32x16_bf16(pa0, v1f[0], oa1, 0, 0, 0);
        oa0 = __builtin_amdgcn_mfma_f32_32x32x16_bf16(pa1, v0f[1], oa0, 0, 0, 0);
        oa1 = __builtin_amdgcn_mfma_f32_32x32x16_bf16(pa1, v1f[1], oa1, 0, 0, 0);
        __builtin_amdgcn_s_setprio(0);

        if (more) {
            #pragma unroll
            for (int c = 0; c < 4; ++c) kf[c] = nk[c];
        }
    }

    // ---- merge partials (exactly additive: same zero shift) ----
    if (s == 1) {
        #pragma unroll
        for (int r = 0; r < 16; ++r) {
            Xo[p][lane][r]      = oa0[r];
            Xo[p][lane][16 + r] = oa1[r];
        }
        Xs[p][lane] = sden;
    }
    __syncthreads();
    if (s == 0) {
        #pragma unroll
        for (int r = 0; r < 16; ++r) {
            oa0[r] += Xo[p][lane][r];
            oa1[r] += Xo[p][lane][16 + r];
        }
        sden += Xs[p][lane];

        if (hi == 0) Sdl[p][lq] = 1.0f / sden;
        __builtin_amdgcn_s_waitcnt(0);   // same-wave LDS visibility

        const int b = bh >> 4, h = bh & 15;
        #pragma unroll
        for (int r = 0; r < 16; ++r) {
            int q = (r & 3) + 8 * (r >> 2) + 4 * hi;
            float inv = Sdl[p][q];
            size_t row = (size_t)(b * L_ + q0 + q) * D_ + h * HD_;
            obuf[row + lq]      = f2bf(oa0[r] * inv);
            obuf[row + 32 + lq] = f2bf(oa1[r] * inv);
        }
    }
}

extern "C" void kernel_launch(void* const* d_in, const int* in_sizes, int n_in,
                              void* d_out, int out_size, void* d_ws, size_t ws_size,
                              hipStream_t stream) {
    const float* x    = (const float*)d_in[0];
    const float* Wqkv = (const float*)d_in[1];
    const float* Wout = (const float*)d_in[2];
    const float* bout = (const float*)d_in[3];
    float* out = (float*)d_out;

    char* ws = (char*)d_ws;
    size_t off = 0;
    unsigned short* xb     = (unsigned short*)(ws + off); off += (size_t)M1_ * D_ * 2;   // 16MB
    unsigned short* wqkvT  = (unsigned short*)(ws + off); off += (size_t)N3_ * D_ * 2;   // 6MB
    unsigned short* woutT  = (unsigned short*)(ws + off); off += (size_t)D_ * D_ * 2;    // 2MB
    unsigned short* qb     = (unsigned short*)(ws + off); off += (size_t)B_ * H_ * L_ * HD_ * 2;
    unsigned short* kb     = (unsigned short*)(ws + off); off += (size_t)B_ * H_ * L_ * HD_ * 2;
    unsigned short* vb     = (unsigned short*)(ws + off); off += (size_t)B_ * H_ * L_ * HD_ * 2;
    unsigned short* attnb  = (unsigned short*)(ws + off); off += (size_t)M1_ * D_ * 2;

    // pass 0: fused conversions (x->bf16, Wqkv^T, Wout^T) — one launch
    prep_kernel<<<dim3(8192 + 3072 + 1024), 256, 0, stream>>>(
        x, Wqkv, Wout, (ushort4*)xb, wqkvT, woutT);

    // pass 1: QKV projection (256x128, 3-buf, 768 blocks), Q pre-scaled
    gemm256_qkv_kernel<<<dim3((M1_ / 256) * (N3_ / 128)), 512, 0, stream>>>(
        xb, wqkvT, qb, kb, vb);

    // pass 2: causal flash attention (kv-split x2, 32 waves/CU)
    attn_kernel<<<dim3(16 * 64), 512, 0, stream>>>(qb, kb, vb, attnb);

    // pass 3: output projection + bias (128^2, 512 blocks = 2/CU)
    gemm_bt_kernel<<<dim3(D_ / 128, M1_ / 128), 256, 0, stream>>>(
        attnb, woutT, out, bout);
}